// Round 6
// baseline (347.256 us; speedup 1.0000x reference)
//
#include <hip/hip_runtime.h>
#include <hip/hip_bf16.h>
#include <math.h>

// B=4, T=2048, C=1024, H=16, D=64. All dims divide tiles exactly.
typedef __bf16 bf16;
typedef __bf16 bf16x8 __attribute__((ext_vector_type(8)));
typedef __bf16 bf16x4 __attribute__((ext_vector_type(4)));
typedef float  f32x4  __attribute__((ext_vector_type(4)));

// async 16B/lane global->LDS. lds base must be wave-uniform; HW adds lane*16.
__device__ __forceinline__ void gld_lds16(const bf16* g, bf16* l) {
    void* gv = (void*)g;  // drop const
    __builtin_amdgcn_global_load_lds(
        (__attribute__((address_space(1))) void*)gv,
        (__attribute__((address_space(3))) void*)l, 16, 0, 0);
}

// ---------------- fp32 -> bf16 elementwise cast ----------------
__global__ void k_cvt_bf16(const float* __restrict__ in, bf16* __restrict__ out, int n4) {
    int i = blockIdx.x * blockDim.x + threadIdx.x;
    if (i < n4) {
        float4 v = ((const float4*)in)[i];
        bf16x4 o;
        o[0] = (bf16)v.x; o[1] = (bf16)v.y; o[2] = (bf16)v.z; o[3] = (bf16)v.w;
        ((bf16x4*)out)[i] = o;
    }
}

// ---------------- fp32 [R][C] -> bf16 [C][R] transpose+cast ----------------
// grid (C/64, R/64), block 256
__global__ void k_transpose_cvt(const float* __restrict__ in, bf16* __restrict__ out,
                                int R, int C) {
    __shared__ float tile[64][68];
    int c0 = blockIdx.x * 64, r0 = blockIdx.y * 64;
    int tid = threadIdx.x;
#pragma unroll
    for (int i = 0; i < 4; ++i) {            // 1024 float4 chunks
        int chunk = tid + i * 256;
        int r = chunk >> 4, c4 = (chunk & 15) * 4;
        float4 v = *(const float4*)(in + (size_t)(r0 + r) * C + c0 + c4);
        tile[r][c4 + 0] = v.x; tile[r][c4 + 1] = v.y;
        tile[r][c4 + 2] = v.z; tile[r][c4 + 3] = v.w;
    }
    __syncthreads();
#pragma unroll
    for (int i = 0; i < 2; ++i) {            // 512 chunks of 8 bf16
        int chunk = tid + i * 256;
        int c = chunk >> 3, k8 = (chunk & 7) * 8;
        bf16x8 v;
#pragma unroll
        for (int j = 0; j < 8; ++j) v[j] = (bf16)tile[k8 + j][c];
        *(bf16x8*)(out + (size_t)(c0 + c) * R + r0 + k8) = v;
    }
}

// ---------------- V slice of qkv -> vt[(bh*64+d)*2048 + t] ----------------
// grid (T/64, B*H), block 256
__global__ void k_transpose_v(const bf16* __restrict__ qkv, bf16* __restrict__ vt) {
    __shared__ bf16 tile[64][72];
    int bh = blockIdx.y, b = bh >> 4, h = bh & 15;
    int t0 = blockIdx.x * 64;
    int tid = threadIdx.x;
    const bf16* src = qkv + (size_t)(b * 2048 + t0) * 3072 + 2048 + h * 64;
#pragma unroll
    for (int i = 0; i < 2; ++i) {
        int chunk = tid + i * 256;
        int t = chunk >> 3, d8 = (chunk & 7) * 8;
        bf16x8 v = *(const bf16x8*)(src + (size_t)t * 3072 + d8);
#pragma unroll
        for (int j = 0; j < 8; ++j) tile[t][d8 + j] = v[j];
    }
    __syncthreads();
#pragma unroll
    for (int i = 0; i < 2; ++i) {
        int chunk = tid + i * 256;
        int d = chunk >> 3, t8 = (chunk & 7) * 8;
        bf16x8 v;
#pragma unroll
        for (int j = 0; j < 8; ++j) v[j] = tile[t8 + j][d];
        *(bf16x8*)(vt + ((size_t)bh * 64 + d) * 2048 + t0 + t8) = v;
    }
}

// ---------------- GEMM: C[M][N] = A[M][K] * Bt[N][K]^T + bias ----------------
// 128x128 block tile, 4 waves (2x2) of 64x64, BK=64 kf-split LDS [2][128][32]
// (bank-uniform), global_load_lds width=16 staging, mfma 16x16x32 bf16.
template <bool OUT_BF16>
__global__ __launch_bounds__(256, 2) void k_gemm(
    const bf16* __restrict__ A, const bf16* __restrict__ Bt,
    const float* __restrict__ bias, void* __restrict__ Cout,
    int M, int N, int K) {
    __shared__ __align__(16) bf16 lA[2][4096];
    __shared__ __align__(16) bf16 lB[2][4096];
    int tid = threadIdx.x;
    int wid = tid >> 6, lane = tid & 63;
    int quad = lane >> 4, l16 = lane & 15;
    int bm = blockIdx.y * 128, bn = blockIdx.x * 128;
    int wm = (wid >> 1) * 64, wn = (wid & 1) * 64;

    f32x4 zero = {0.f, 0.f, 0.f, 0.f};
    f32x4 acc[4][4];
#pragma unroll
    for (int i = 0; i < 4; ++i)
#pragma unroll
        for (int j = 0; j < 4; ++j) acc[i][j] = zero;

    for (int k0 = 0; k0 < K; k0 += 64) {
        __syncthreads();
#pragma unroll
        for (int i = 0; i < 4; ++i) {
            int j = (wid * 4 + i) * 64 + lane;          // 0..1023
            int kf = j >> 9, row = (j & 511) >> 2, c8 = (j & 3) * 8;
            gld_lds16(A  + (size_t)(bm + row) * K + k0 + kf * 32 + c8, &lA[0][0] + (wid * 4 + i) * 512);
            gld_lds16(Bt + (size_t)(bn + row) * K + k0 + kf * 32 + c8, &lB[0][0] + (wid * 4 + i) * 512);
        }
        __syncthreads();
#pragma unroll
        for (int kk = 0; kk < 2; ++kk) {
            bf16x8 af[4], bg[4];
#pragma unroll
            for (int i = 0; i < 4; ++i) {
                af[i] = *(const bf16x8*)(&lA[kk][(wm + i * 16 + l16) * 32 + quad * 8]);
                bg[i] = *(const bf16x8*)(&lB[kk][(wn + i * 16 + l16) * 32 + quad * 8]);
            }
#pragma unroll
            for (int i = 0; i < 4; ++i)
#pragma unroll
                for (int j = 0; j < 4; ++j)
                    acc[i][j] = __builtin_amdgcn_mfma_f32_16x16x32_bf16(af[i], bg[j], acc[i][j], 0, 0, 0);
        }
    }
#pragma unroll
    for (int i = 0; i < 4; ++i) {
#pragma unroll
        for (int j = 0; j < 4; ++j) {
            int col = bn + wn + j * 16 + l16;
            float bv = bias ? bias[col] : 0.f;
#pragma unroll
            for (int r = 0; r < 4; ++r) {
                int row = bm + wm + i * 16 + quad * 4 + r;
                float v = acc[i][j][r] + bv;
                if (OUT_BF16) ((bf16*)Cout)[(size_t)row * N + col] = (bf16)v;
                else          ((float*)Cout)[(size_t)row * N + col] = v;
            }
        }
    }
}

// ---------------- flash attention (v6) ----------------
// Block = 128 q-rows, 4 waves x 32 rows. K/V double-buffered kf-split LDS.
// S computed transposed (mfma(K,Q)). P round-trip through a per-wave 16x64
// XOR-SWIZZLED buffer (2KB/wave, bank-floor); the two 16-row halves reuse it
// sequentially (same-wave DS ordering). Total LDS 40KB -> 4 blocks/CU.
// exp2 domain (log2e folded into Q prescale, no shift). Row sums via an
// all-ones MFMA B-fragment (o1 = P*1), C-layout matches o.
__global__ __launch_bounds__(256, 4) void k_attn(
    const bf16* __restrict__ qkv,   // [B*T][3072]
    const bf16* __restrict__ vt,    // [(bh*64+d)*2048 + t]
    bf16* __restrict__ y) {         // [B*T][1024]
    __shared__ __align__(16) bf16 lK[2][4096];
    __shared__ __align__(16) bf16 lV[2][4096];
    __shared__ __align__(16) bf16 lP[4][1024];   // per-wave [q 16][t 64], swizzled

    const int T = 2048, CQ = 3072;
    const float QSCALE = 0.125f * 1.44269504088896f;  // fold log2e: use exp2
    int tid = threadIdx.x, wid = tid >> 6, lane = tid & 63;
    int quad = lane >> 4, l16 = lane & 15;
    // bh spread so each XCD's 8 bh (4MB K+V) fits its L2; heavy qb first.
    int x = blockIdx.x;
    int bh = ((x & 7) << 3) | ((x >> 3) & 7);
    int qb = 15 - (x >> 6);                    // 128-row block index, 0..15
    int b = bh >> 4, h = bh & 15;
    int q0 = qb * 128;
    int rb = qb * 4 + wid;                     // this wave's 32-row block idx
    int mdiag = rb >> 1;                       // k-tile containing diagonal
    int ntiles = qb * 2 + 2;                   // tiles staged by this block

    const bf16* qbase = qkv + (size_t)(b * T + q0 + wid * 32) * CQ + h * 64;
    const bf16* kbase = qkv + (size_t)(b * T) * CQ + 1024 + h * 64;
    const bf16* vbase = vt + (size_t)bh * 64 * T;
    bf16* lPw = lP[wid];

    // stage K/V tile kt into buffer buf: [kf][64][32], linear chunk mapping
    auto stage = [&](int kt, int buf) {
        int t0 = kt * 64;
#pragma unroll
        for (int i = 0; i < 2; ++i) {
            int j = (wid * 2 + i) * 64 + lane;         // 0..511
            int kf = j >> 8, r = (j & 255) >> 2, c8 = (j & 3) * 8;
            gld_lds16(kbase + (size_t)(t0 + r) * CQ + kf * 32 + c8, &lK[buf][(wid * 2 + i) * 512]);
            gld_lds16(vbase + (size_t)r * T + t0 + kf * 32 + c8,    &lV[buf][(wid * 2 + i) * 512]);
        }
    };

    // Q B-frags (2 row-halves of this wave's 32 rows), prescaled
    bf16x8 qf[2][2];
#pragma unroll
    for (int qi = 0; qi < 2; ++qi)
#pragma unroll
        for (int kf = 0; kf < 2; ++kf) {
            bf16x8 v = *(const bf16x8*)(qbase + (size_t)(qi * 16 + l16) * CQ + kf * 32 + quad * 8);
#pragma unroll
            for (int j = 0; j < 8; ++j) v[j] = (bf16)((float)v[j] * QSCALE);
            qf[qi][kf] = v;
        }

    bf16x8 ones;
#pragma unroll
    for (int j = 0; j < 8; ++j) ones[j] = (bf16)1.0f;

    f32x4 zero = {0.f, 0.f, 0.f, 0.f};
    f32x4 o[2][4], o1[2];
#pragma unroll
    for (int qi = 0; qi < 2; ++qi) {
        o1[qi] = zero;
#pragma unroll
        for (int i = 0; i < 4; ++i) o[qi][i] = zero;
    }

    stage(0, 0);
    for (int kt = 0; kt < ntiles; ++kt) {
        __syncthreads();                       // buf[kt&1] ready (vmcnt drained)
        if (kt + 1 < ntiles) stage(kt + 1, (kt + 1) & 1);
        if (kt > mdiag) continue;              // no live cols; still hit barriers
        const bf16* Kb = lK[kt & 1];
        const bf16* Vb = lV[kt & 1];
        bool diag = (kt == mdiag);
        bool half = diag && !(rb & 1);         // even rb: only t 0..31 live
        int in_hi = half ? 2 : 4;

        // S^T = K (Q*scale)^T : lane holds q=l16, t = in*16+quad*4+r (log2 dom)
        f32x4 s[2][4];
#pragma unroll
        for (int qi = 0; qi < 2; ++qi)
#pragma unroll
            for (int in = 0; in < 4; ++in) s[qi][in] = zero;
        for (int kf = 0; kf < 2; ++kf)
            for (int in = 0; in < in_hi; ++in) {
                bf16x8 kb = *(const bf16x8*)(Kb + kf * 2048 + (in * 16 + l16) * 32 + quad * 8);
#pragma unroll
                for (int qi = 0; qi < 2; ++qi)
                    s[qi][in] = __builtin_amdgcn_mfma_f32_16x16x32_bf16(kb, qf[qi][kf], s[qi][in], 0, 0, 0);
            }

        // V B-frags hoisted (shared by both qi halves)
        bf16x8 vb[2][4];
#pragma unroll
        for (int kf = 0; kf < 2; ++kf)
#pragma unroll
            for (int dn = 0; dn < 4; ++dn)
                vb[kf][dn] = *(const bf16x8*)(Vb + kf * 2048 + (dn * 16 + l16) * 32 + quad * 8);

        int rl0 = (rb * 32) - kt * 64;         // q offset rel to tile t-base
        int sw = (l16 & 7);                    // row XOR swizzle key
#pragma unroll
        for (int qi = 0; qi < 2; ++qi) {
            int qloc = rl0 + qi * 16 + l16;
            // p = exp2(s); causal mask on diag; packed b64 swizzled write
#pragma unroll
            for (int in = 0; in < 4; ++in) {
                bf16x4 pk4;
                if (in >= in_hi) {
                    pk4[0] = pk4[1] = pk4[2] = pk4[3] = (bf16)0.f;
                } else {
#pragma unroll
                    for (int r = 0; r < 4; ++r) {
                        float e = exp2f(s[qi][in][r]);
                        if (diag) {
                            int tloc = in * 16 + quad * 4 + r;
                            if (tloc > qloc) e = 0.f;
                        }
                        pk4[r] = (bf16)e;
                    }
                }
                int tb = in * 2 + (quad >> 1);
                *(bf16x4*)(lPw + l16 * 64 + ((tb ^ sw) << 3) + (quad & 1) * 4) = pk4;
            }
            // P A-frags (same-wave LDS, in-order DS), O += P V ; o1 += P*1
#pragma unroll
            for (int kf = 0; kf < 2; ++kf) {
                int tbr = kf * 4 + quad;
                bf16x8 pa = *(const bf16x8*)(lPw + l16 * 64 + ((tbr ^ sw) << 3));
                o1[qi] = __builtin_amdgcn_mfma_f32_16x16x32_bf16(pa, ones, o1[qi], 0, 0, 0);
#pragma unroll
                for (int dn = 0; dn < 4; ++dn)
                    o[qi][dn] = __builtin_amdgcn_mfma_f32_16x16x32_bf16(pa, vb[kf][dn], o[qi][dn], 0, 0, 0);
            }
        }
    }

    // epilogue: o1[qi][r] = row sum for q-row quad*4+r (same C-layout as o)
#pragma unroll
    for (int qi = 0; qi < 2; ++qi)
#pragma unroll
        for (int r = 0; r < 4; ++r) {
            float li = 1.f / o1[qi][r];
            int row = q0 + wid * 32 + qi * 16 + quad * 4 + r;
#pragma unroll
            for (int dn = 0; dn < 4; ++dn) {
                float v = o[qi][dn][r] * li;
                y[(size_t)(b * T + row) * 1024 + h * 64 + dn * 16 + l16] = (bf16)v;
            }
        }
}

extern "C" void kernel_launch(void* const* d_in, const int* in_sizes, int n_in,
                              void* d_out, int out_size, void* d_ws, size_t ws_size,
                              hipStream_t stream) {
    const float* x     = (const float*)d_in[0];
    const float* w_qkv = (const float*)d_in[1];
    const float* b_qkv = (const float*)d_in[2];
    const float* w_out = (const float*)d_in[3];
    const float* b_out = (const float*)d_in[4];
    float* out = (float*)d_out;

    const int B = 4, T = 2048, C = 1024, H = 16;
    const int M = B * T;  // 8192

    // workspace layout (88 MB total); vt aliases xb (xb dead after GEMM1)
    char* ws = (char*)d_ws;
    bf16* xb    = (bf16*)(ws);                        // 16 MB
    bf16* wqkvT = (bf16*)(ws + (16ull << 20));        //  6 MB
    bf16* woutT = (bf16*)(ws + (22ull << 20));        //  2 MB
    bf16* qkvb  = (bf16*)(ws + (24ull << 20));        // 48 MB
    bf16* yb    = (bf16*)(ws + (72ull << 20));        // 16 MB
    bf16* vtb   = xb;

    k_cvt_bf16<<<(M * C / 4 + 255) / 256, 256, 0, stream>>>(x, xb, M * C / 4);
    k_transpose_cvt<<<dim3(3 * C / 64, C / 64), 256, 0, stream>>>(w_qkv, wqkvT, C, 3 * C);
    k_transpose_cvt<<<dim3(C / 64, C / 64), 256, 0, stream>>>(w_out, woutT, C, C);
    k_gemm<true><<<dim3(3 * C / 128, M / 128), 256, 0, stream>>>(xb, wqkvT, b_qkv, qkvb, M, 3 * C, C);
    k_transpose_v<<<dim3(T / 64, B * H), 256, 0, stream>>>(qkvb, vtb);
    k_attn<<<dim3(1024, 1), 256, 0, stream>>>(qkvb, vtb, yb);
    k_gemm<false><<<dim3(C / 128, M / 128), 256, 0, stream>>>(yb, woutT, b_out, out, M, C, C);
}

// Round 7
// 299.311 us; speedup vs baseline: 1.1602x; 1.1602x over previous
//
#include <hip/hip_runtime.h>
#include <hip/hip_bf16.h>
#include <math.h>

// B=4, T=2048, C=1024, H=16, D=64. All dims divide tiles exactly.
typedef __bf16 bf16;
typedef __bf16 bf16x8 __attribute__((ext_vector_type(8)));
typedef __bf16 bf16x4 __attribute__((ext_vector_type(4)));
typedef float  f32x4  __attribute__((ext_vector_type(4)));

// async 16B/lane global->LDS. lds base must be wave-uniform; HW adds lane*16.
__device__ __forceinline__ void gld_lds16(const bf16* g, bf16* l) {
    void* gv = (void*)g;  // drop const
    __builtin_amdgcn_global_load_lds(
        (__attribute__((address_space(1))) void*)gv,
        (__attribute__((address_space(3))) void*)l, 16, 0, 0);
}

// ---------------- fp32 -> bf16 elementwise cast ----------------
__global__ void k_cvt_bf16(const float* __restrict__ in, bf16* __restrict__ out, int n4) {
    int i = blockIdx.x * blockDim.x + threadIdx.x;
    if (i < n4) {
        float4 v = ((const float4*)in)[i];
        bf16x4 o;
        o[0] = (bf16)v.x; o[1] = (bf16)v.y; o[2] = (bf16)v.z; o[3] = (bf16)v.w;
        ((bf16x4*)out)[i] = o;
    }
}

// ---------------- fp32 [R][C] -> bf16 [C][R] transpose+cast ----------------
// grid (C/64, R/64), block 256
__global__ void k_transpose_cvt(const float* __restrict__ in, bf16* __restrict__ out,
                                int R, int C) {
    __shared__ float tile[64][68];
    int c0 = blockIdx.x * 64, r0 = blockIdx.y * 64;
    int tid = threadIdx.x;
#pragma unroll
    for (int i = 0; i < 4; ++i) {            // 1024 float4 chunks
        int chunk = tid + i * 256;
        int r = chunk >> 4, c4 = (chunk & 15) * 4;
        float4 v = *(const float4*)(in + (size_t)(r0 + r) * C + c0 + c4);
        tile[r][c4 + 0] = v.x; tile[r][c4 + 1] = v.y;
        tile[r][c4 + 2] = v.z; tile[r][c4 + 3] = v.w;
    }
    __syncthreads();
#pragma unroll
    for (int i = 0; i < 2; ++i) {            // 512 chunks of 8 bf16
        int chunk = tid + i * 256;
        int c = chunk >> 3, k8 = (chunk & 7) * 8;
        bf16x8 v;
#pragma unroll
        for (int j = 0; j < 8; ++j) v[j] = (bf16)tile[k8 + j][c];
        *(bf16x8*)(out + (size_t)(c0 + c) * R + r0 + k8) = v;
    }
}

// ---------------- V slice of qkv -> vt[(bh*64+d)*2048 + t] ----------------
// grid (T/64, B*H), block 256
__global__ void k_transpose_v(const bf16* __restrict__ qkv, bf16* __restrict__ vt) {
    __shared__ bf16 tile[64][72];
    int bh = blockIdx.y, b = bh >> 4, h = bh & 15;
    int t0 = blockIdx.x * 64;
    int tid = threadIdx.x;
    const bf16* src = qkv + (size_t)(b * 2048 + t0) * 3072 + 2048 + h * 64;
#pragma unroll
    for (int i = 0; i < 2; ++i) {
        int chunk = tid + i * 256;
        int t = chunk >> 3, d8 = (chunk & 7) * 8;
        bf16x8 v = *(const bf16x8*)(src + (size_t)t * 3072 + d8);
#pragma unroll
        for (int j = 0; j < 8; ++j) tile[t][d8 + j] = v[j];
    }
    __syncthreads();
#pragma unroll
    for (int i = 0; i < 2; ++i) {
        int chunk = tid + i * 256;
        int d = chunk >> 3, t8 = (chunk & 7) * 8;
        bf16x8 v;
#pragma unroll
        for (int j = 0; j < 8; ++j) v[j] = tile[t8 + j][d];
        *(bf16x8*)(vt + ((size_t)bh * 64 + d) * 2048 + t0 + t8) = v;
    }
}

// ---------------- GEMM: C[M][N] = A[M][K] * Bt[N][K]^T + bias ----------------
// 128x128 block tile, 4 waves (2x2) of 64x64, BK=64 kf-split LDS [2][128][32]
// (bank-uniform), global_load_lds width=16 staging, mfma 16x16x32 bf16.
template <bool OUT_BF16>
__global__ __launch_bounds__(256, 2) void k_gemm(
    const bf16* __restrict__ A, const bf16* __restrict__ Bt,
    const float* __restrict__ bias, void* __restrict__ Cout,
    int M, int N, int K) {
    __shared__ __align__(16) bf16 lA[2][4096];
    __shared__ __align__(16) bf16 lB[2][4096];
    int tid = threadIdx.x;
    int wid = tid >> 6, lane = tid & 63;
    int quad = lane >> 4, l16 = lane & 15;
    int bm = blockIdx.y * 128, bn = blockIdx.x * 128;
    int wm = (wid >> 1) * 64, wn = (wid & 1) * 64;

    f32x4 zero = {0.f, 0.f, 0.f, 0.f};
    f32x4 acc[4][4];
#pragma unroll
    for (int i = 0; i < 4; ++i)
#pragma unroll
        for (int j = 0; j < 4; ++j) acc[i][j] = zero;

    for (int k0 = 0; k0 < K; k0 += 64) {
        __syncthreads();
#pragma unroll
        for (int i = 0; i < 4; ++i) {
            int j = (wid * 4 + i) * 64 + lane;          // 0..1023
            int kf = j >> 9, row = (j & 511) >> 2, c8 = (j & 3) * 8;
            gld_lds16(A  + (size_t)(bm + row) * K + k0 + kf * 32 + c8, &lA[0][0] + (wid * 4 + i) * 512);
            gld_lds16(Bt + (size_t)(bn + row) * K + k0 + kf * 32 + c8, &lB[0][0] + (wid * 4 + i) * 512);
        }
        __syncthreads();
#pragma unroll
        for (int kk = 0; kk < 2; ++kk) {
            bf16x8 af[4], bg[4];
#pragma unroll
            for (int i = 0; i < 4; ++i) {
                af[i] = *(const bf16x8*)(&lA[kk][(wm + i * 16 + l16) * 32 + quad * 8]);
                bg[i] = *(const bf16x8*)(&lB[kk][(wn + i * 16 + l16) * 32 + quad * 8]);
            }
#pragma unroll
            for (int i = 0; i < 4; ++i)
#pragma unroll
                for (int j = 0; j < 4; ++j)
                    acc[i][j] = __builtin_amdgcn_mfma_f32_16x16x32_bf16(af[i], bg[j], acc[i][j], 0, 0, 0);
        }
    }
#pragma unroll
    for (int i = 0; i < 4; ++i) {
#pragma unroll
        for (int j = 0; j < 4; ++j) {
            int col = bn + wn + j * 16 + l16;
            float bv = bias ? bias[col] : 0.f;
#pragma unroll
            for (int r = 0; r < 4; ++r) {
                int row = bm + wm + i * 16 + quad * 4 + r;
                float v = acc[i][j][r] + bv;
                if (OUT_BF16) ((bf16*)Cout)[(size_t)row * N + col] = (bf16)v;
                else          ((float*)Cout)[(size_t)row * N + col] = v;
            }
        }
    }
}

// ---------------- flash attention (v7) ----------------
// Block = 128 q-rows, 4 waves x 32 rows. K/V double-buffered kf-split LDS.
// S computed transposed (mfma(K,Q)). P round-trip through a per-wave 16x64
// XOR-swizzled buffer (2KB/wave; b64 writes 2-way, b128 reads uniform); the
// two 16-row halves reuse it sequentially (same-wave DS ordering). Total LDS
// 40KB -> 4 blocks/CU. exp2 domain (log2e folded into Q prescale). lsum as
// lane scalars (NOT ones-MFMA: R6 showed the extra acc regs cause scratch
// spills). launch_bounds(256,3): reg cap 160; actual alloc ~<=128 lets HW
// run 4 blocks/CU without spilling (2nd arg caps allocator, not occupancy).
__global__ __launch_bounds__(256, 3) void k_attn(
    const bf16* __restrict__ qkv,   // [B*T][3072]
    const bf16* __restrict__ vt,    // [(bh*64+d)*2048 + t]
    bf16* __restrict__ y) {         // [B*T][1024]
    __shared__ __align__(16) bf16 lK[2][4096];
    __shared__ __align__(16) bf16 lV[2][4096];
    __shared__ __align__(16) bf16 lP[4][1024];   // per-wave [q 16][t 64], swizzled

    const int T = 2048, CQ = 3072;
    const float QSCALE = 0.125f * 1.44269504088896f;  // fold log2e: use exp2
    int tid = threadIdx.x, wid = tid >> 6, lane = tid & 63;
    int quad = lane >> 4, l16 = lane & 15;
    // bh spread so each XCD's 8 bh (4MB K+V) fits its L2; heavy qb first.
    int x = blockIdx.x;
    int bh = ((x & 7) << 3) | ((x >> 3) & 7);
    int qb = 15 - (x >> 6);                    // 128-row block index, 0..15
    int b = bh >> 4, h = bh & 15;
    int q0 = qb * 128;
    int rb = qb * 4 + wid;                     // this wave's 32-row block idx
    int mdiag = rb >> 1;                       // k-tile containing diagonal
    int ntiles = qb * 2 + 2;                   // tiles staged by this block

    const bf16* qbase = qkv + (size_t)(b * T + q0 + wid * 32) * CQ + h * 64;
    const bf16* kbase = qkv + (size_t)(b * T) * CQ + 1024 + h * 64;
    const bf16* vbase = vt + (size_t)bh * 64 * T;
    bf16* lPw = lP[wid];

    // stage K/V tile kt into buffer buf: [kf][64][32], linear chunk mapping
    auto stage = [&](int kt, int buf) {
        int t0 = kt * 64;
#pragma unroll
        for (int i = 0; i < 2; ++i) {
            int j = (wid * 2 + i) * 64 + lane;         // 0..511
            int kf = j >> 8, r = (j & 255) >> 2, c8 = (j & 3) * 8;
            gld_lds16(kbase + (size_t)(t0 + r) * CQ + kf * 32 + c8, &lK[buf][(wid * 2 + i) * 512]);
            gld_lds16(vbase + (size_t)r * T + t0 + kf * 32 + c8,    &lV[buf][(wid * 2 + i) * 512]);
        }
    };

    // Q B-frags (2 row-halves of this wave's 32 rows), prescaled
    bf16x8 qf[2][2];
#pragma unroll
    for (int qi = 0; qi < 2; ++qi)
#pragma unroll
        for (int kf = 0; kf < 2; ++kf) {
            bf16x8 v = *(const bf16x8*)(qbase + (size_t)(qi * 16 + l16) * CQ + kf * 32 + quad * 8);
#pragma unroll
            for (int j = 0; j < 8; ++j) v[j] = (bf16)((float)v[j] * QSCALE);
            qf[qi][kf] = v;
        }

    f32x4 zero = {0.f, 0.f, 0.f, 0.f};
    f32x4 o[2][4];
    float lsum[2] = {0.f, 0.f};
#pragma unroll
    for (int qi = 0; qi < 2; ++qi)
#pragma unroll
        for (int i = 0; i < 4; ++i) o[qi][i] = zero;

    stage(0, 0);
    for (int kt = 0; kt < ntiles; ++kt) {
        __syncthreads();                       // buf[kt&1] ready (vmcnt drained)
        if (kt + 1 < ntiles) stage(kt + 1, (kt + 1) & 1);
        if (kt > mdiag) continue;              // no live cols; still hit barriers
        const bf16* Kb = lK[kt & 1];
        const bf16* Vb = lV[kt & 1];
        bool diag = (kt == mdiag);
        bool half = diag && !(rb & 1);         // even rb: only t 0..31 live
        int in_hi = half ? 2 : 4;

        // S^T = K (Q*scale)^T : lane holds q=l16, t = in*16+quad*4+r (log2 dom)
        f32x4 s[2][4];
#pragma unroll
        for (int qi = 0; qi < 2; ++qi)
#pragma unroll
            for (int in = 0; in < 4; ++in) s[qi][in] = zero;
        for (int kf = 0; kf < 2; ++kf)
            for (int in = 0; in < in_hi; ++in) {
                bf16x8 kb = *(const bf16x8*)(Kb + kf * 2048 + (in * 16 + l16) * 32 + quad * 8);
#pragma unroll
                for (int qi = 0; qi < 2; ++qi)
                    s[qi][in] = __builtin_amdgcn_mfma_f32_16x16x32_bf16(kb, qf[qi][kf], s[qi][in], 0, 0, 0);
            }

        // V B-frags hoisted (shared by both qi halves)
        bf16x8 vb[2][4];
#pragma unroll
        for (int kf = 0; kf < 2; ++kf)
#pragma unroll
            for (int dn = 0; dn < 4; ++dn)
                vb[kf][dn] = *(const bf16x8*)(Vb + kf * 2048 + (dn * 16 + l16) * 32 + quad * 8);

        int rl0 = (rb * 32) - kt * 64;         // q offset rel to tile t-base
        int sw = (l16 & 7);                    // row XOR swizzle key
#pragma unroll
        for (int qi = 0; qi < 2; ++qi) {
            int qloc = rl0 + qi * 16 + l16;
            // p = exp2(s); causal mask on diag; packed b64 swizzled write
#pragma unroll
            for (int in = 0; in < 4; ++in) {
                bf16x4 pk4;
                if (in >= in_hi) {
                    pk4[0] = pk4[1] = pk4[2] = pk4[3] = (bf16)0.f;
                } else {
#pragma unroll
                    for (int r = 0; r < 4; ++r) {
                        float e = exp2f(s[qi][in][r]);
                        if (diag) {
                            int tloc = in * 16 + quad * 4 + r;
                            if (tloc > qloc) e = 0.f;
                        }
                        lsum[qi] += e;
                        pk4[r] = (bf16)e;
                    }
                }
                int tb = in * 2 + (quad >> 1);
                *(bf16x4*)(lPw + l16 * 64 + ((tb ^ sw) << 3) + (quad & 1) * 4) = pk4;
            }
            // P A-frags (same-wave LDS, in-order DS), O += P V
#pragma unroll
            for (int kf = 0; kf < 2; ++kf) {
                int tbr = kf * 4 + quad;
                bf16x8 pa = *(const bf16x8*)(lPw + l16 * 64 + ((tbr ^ sw) << 3));
#pragma unroll
                for (int dn = 0; dn < 4; ++dn)
                    o[qi][dn] = __builtin_amdgcn_mfma_f32_16x16x32_bf16(pa, vb[kf][dn], o[qi][dn], 0, 0, 0);
            }
        }
    }

    // epilogue: lsum[qi] is lane-partial over t for q-row l16; quads hold
    // disjoint t-subsets -> reduce with xor 16/32, broadcast to C-layout rows.
    float linv[2];
#pragma unroll
    for (int qi = 0; qi < 2; ++qi) {
        float l = lsum[qi];
        l += __shfl_xor(l, 16, 64);
        l += __shfl_xor(l, 32, 64);
        linv[qi] = 1.f / l;
    }
#pragma unroll
    for (int qi = 0; qi < 2; ++qi)
#pragma unroll
        for (int r = 0; r < 4; ++r) {
            float li = __shfl(linv[qi], quad * 4 + r, 64);  // linv for q=quad*4+r
            int row = q0 + wid * 32 + qi * 16 + quad * 4 + r;
#pragma unroll
            for (int dn = 0; dn < 4; ++dn) {
                float v = o[qi][dn][r] * li;
                y[(size_t)(b * T + row) * 1024 + h * 64 + dn * 16 + l16] = (bf16)v;
            }
        }
}

extern "C" void kernel_launch(void* const* d_in, const int* in_sizes, int n_in,
                              void* d_out, int out_size, void* d_ws, size_t ws_size,
                              hipStream_t stream) {
    const float* x     = (const float*)d_in[0];
    const float* w_qkv = (const float*)d_in[1];
    const float* b_qkv = (const float*)d_in[2];
    const float* w_out = (const float*)d_in[3];
    const float* b_out = (const float*)d_in[4];
    float* out = (float*)d_out;

    const int B = 4, T = 2048, C = 1024, H = 16;
    const int M = B * T;  // 8192

    // workspace layout (88 MB total); vt aliases xb (xb dead after GEMM1)
    char* ws = (char*)d_ws;
    bf16* xb    = (bf16*)(ws);                        // 16 MB
    bf16* wqkvT = (bf16*)(ws + (16ull << 20));        //  6 MB
    bf16* woutT = (bf16*)(ws + (22ull << 20));        //  2 MB
    bf16* qkvb  = (bf16*)(ws + (24ull << 20));        // 48 MB
    bf16* yb    = (bf16*)(ws + (72ull << 20));        // 16 MB
    bf16* vtb   = xb;

    k_cvt_bf16<<<(M * C / 4 + 255) / 256, 256, 0, stream>>>(x, xb, M * C / 4);
    k_transpose_cvt<<<dim3(3 * C / 64, C / 64), 256, 0, stream>>>(w_qkv, wqkvT, C, 3 * C);
    k_transpose_cvt<<<dim3(C / 64, C / 64), 256, 0, stream>>>(w_out, woutT, C, C);
    k_gemm<true><<<dim3(3 * C / 128, M / 128), 256, 0, stream>>>(xb, wqkvT, b_qkv, qkvb, M, 3 * C, C);
    k_transpose_v<<<dim3(T / 64, B * H), 256, 0, stream>>>(qkvb, vtb);
    k_attn<<<dim3(1024, 1), 256, 0, stream>>>(qkvb, vtb, yb);
    k_gemm<false><<<dim3(C / 128, M / 128), 256, 0, stream>>>(yb, woutT, b_out, out, M, C, C);
}